// Round 2
// baseline (453.022 us; speedup 1.0000x reference)
//
#include <hip/hip_runtime.h>

// MHA: B=2, S=2048, D=1024, H=16, hd=64. fp32 in/out, bf16 MFMA internally.
// R1: attn rewrite — S^T MFMA layout (one q-col per lane), barrier-free per-wave
// P buffer, BK=64, float4 mask loads, packed ds_write_b64 P staging.

typedef __bf16 bf16;
typedef __bf16 bf16x4 __attribute__((ext_vector_type(4)));
typedef __bf16 bf16x8 __attribute__((ext_vector_type(8)));
typedef float f32x4 __attribute__((ext_vector_type(4)));

#define MFMA(a, b, c) __builtin_amdgcn_mfma_f32_16x16x32_bf16((a), (b), (c), 0, 0, 0)

// ---------------- cast fp32 -> bf16, 4 elems/thread ----------------
__global__ void cast4_kernel(const float* __restrict__ in, bf16* __restrict__ out, int n4) {
    int i = blockIdx.x * blockDim.x + threadIdx.x;
    if (i < n4) {
        float4 v = ((const float4*)in)[i];
        bf16x4 o = {(bf16)v.x, (bf16)v.y, (bf16)v.z, (bf16)v.w};
        ((bf16x4*)out)[i] = o;
    }
}

// ---------------- transpose + cast: in [R,C] fp32 -> out [C,R] bf16 ----------------
__global__ void transpose_cast_kernel(const float* __restrict__ in, bf16* __restrict__ out,
                                      int R, int C) {
    __shared__ float tile[32][33];
    int bx = blockIdx.x * 32;
    int by = blockIdx.y * 32;
    int tx = threadIdx.x, ty = threadIdx.y;  // (32,8)
    for (int i = 0; i < 32; i += 8)
        tile[ty + i][tx] = in[(size_t)(by + ty + i) * C + bx + tx];
    __syncthreads();
    for (int i = 0; i < 32; i += 8)
        out[(size_t)(bx + ty + i) * R + by + tx] = (bf16)tile[tx][ty + i];
}

// ---------------- GEMM1: X[4096,1024] @ Wqkv -> scatter Q,K,VT (bf16) ----------------
#define LDK 40

__global__ __launch_bounds__(256) void gemm_qkv_kernel(
    const bf16* __restrict__ A, const bf16* __restrict__ BT,
    const float* __restrict__ bias,
    bf16* __restrict__ Q, bf16* __restrict__ K, bf16* __restrict__ VT) {
    const int KDIM = 1024;
    __shared__ bf16 As[128 * LDK];
    __shared__ bf16 Bs[128 * LDK];
    int bm = blockIdx.x, bn = blockIdx.y;
    int t = threadIdx.x;
    int w = t >> 6, lane = t & 63, g = lane >> 4, l16 = lane & 15;
    int wm = (w >> 1) * 64, wn = (w & 1) * 64;
    f32x4 acc[4][4] = {};
    const bf16* Ablk = A + (size_t)(bm * 128) * KDIM;
    const bf16* Bblk = BT + (size_t)(bn * 128) * KDIM;

    for (int kb = 0; kb < KDIM; kb += 32) {
        __syncthreads();
        for (int c = t; c < 512; c += 256) {
            int row = c >> 2, cc = c & 3;
            *(bf16x8*)(&As[row * LDK + cc * 8]) =
                *(const bf16x8*)(&Ablk[(size_t)row * KDIM + kb + cc * 8]);
            *(bf16x8*)(&Bs[row * LDK + cc * 8]) =
                *(const bf16x8*)(&Bblk[(size_t)row * KDIM + kb + cc * 8]);
        }
        __syncthreads();
        bf16x8 af[4], bfr[4];
        for (int mi = 0; mi < 4; mi++)
            af[mi] = *(const bf16x8*)(&As[(wm + mi * 16 + l16) * LDK + g * 8]);
        for (int ni = 0; ni < 4; ni++)
            bfr[ni] = *(const bf16x8*)(&Bs[(wn + ni * 16 + l16) * LDK + g * 8]);
        for (int mi = 0; mi < 4; mi++)
            for (int ni = 0; ni < 4; ni++)
                acc[mi][ni] = MFMA(af[mi], bfr[ni], acc[mi][ni]);
    }

    for (int mi = 0; mi < 4; mi++) {
        for (int ni = 0; ni < 4; ni++) {
            int col = bn * 128 + wn + ni * 16 + l16;
            float bv = bias[col];
            int h = col / 192, tt = col % 192;
            for (int r = 0; r < 4; r++) {
                int row = bm * 128 + wm + mi * 16 + g * 4 + r;
                float v = acc[mi][ni][r] + bv;
                int b = row >> 11, s = row & 2047;
                size_t bh = (size_t)(b * 16 + h);
                if (tt < 64)
                    Q[(bh * 2048 + s) * 64 + tt] = (bf16)v;
                else if (tt < 128)
                    K[(bh * 2048 + s) * 64 + (tt - 64)] = (bf16)v;
                else
                    VT[(bh * 64 + (tt - 128)) * 2048 + s] = (bf16)v;
            }
        }
    }
}

// ---------------- flash attention (R1) ----------------
// grid = 1024 (32 bh * 32 q-tiles of 64), block = 256 (4 waves x 16 q-rows).
// Scores computed TRANSPOSED: D[m=s][n=q] = MFMA(K_frag, Q_frag). Each lane then
// holds 16 score elems (4 s-subtiles x 4 consecutive s) for ONE q-col (l16).
// Softmax: in-lane tree + 2 shfl_xor (16,32). P^T staged per-wave in LDS with
// packed b64 writes, read back as A-frag b128. NO barriers in the K-loop.
#define PLD 72  // LDS row stride (elems): 144 B, keeps b128 reads 16B-aligned

__global__ __launch_bounds__(256) void attn_kernel(
    const bf16* __restrict__ Q, const bf16* __restrict__ K,
    const bf16* __restrict__ VT, const float* __restrict__ mask,
    bf16* __restrict__ vals) {
    int blk = blockIdx.x;
    int qt = blk & 31, bh = blk >> 5;
    int w = threadIdx.x >> 6, lane = threadIdx.x & 63, g = lane >> 4, l16 = lane & 15;
    int qw = qt * 64 + w * 16;
    const bf16* Qp = Q + (size_t)bh * 2048 * 64;
    const bf16* Kp = K + (size_t)bh * 2048 * 64;
    const bf16* Vp = VT + (size_t)bh * 64 * 2048;

    // Q as B-frag: B[n=q=l16][k=d=g*8+j], two d-halves
    bf16x8 q0 = *(const bf16x8*)(&Qp[(size_t)(qw + l16) * 64 + g * 8]);
    bf16x8 q1 = *(const bf16x8*)(&Qp[(size_t)(qw + l16) * 64 + 32 + g * 8]);

    f32x4 o[4] = {};
    float m = -1e30f, l = 0.f;  // per-lane state for q-col l16 (replicated over g)

    __shared__ bf16 Pl[4][16 * PLD];
    bf16* Pw = Pl[w];
    const float* mrow = mask + (size_t)(qw + l16) * 2048;

    for (int kb = 0; kb < 2048; kb += 64) {
        // S^T: 4 s-subtiles of 16; lane holds (s = kb + t*16 + g*4 + r, q = qw+l16)
        f32x4 st[4];
#pragma unroll
        for (int t = 0; t < 4; t++) {
            const bf16* kr = &Kp[(size_t)(kb + t * 16 + l16) * 64];
            bf16x8 k0 = *(const bf16x8*)(&kr[g * 8]);
            bf16x8 k1 = *(const bf16x8*)(&kr[32 + g * 8]);
            f32x4 s = {};
            s = MFMA(k0, q0, s);
            s = MFMA(k1, q1, s);
            st[t] = s;
        }
        // scale + mask (float4: 4 consecutive s per lane)
        float sc[16];
#pragma unroll
        for (int t = 0; t < 4; t++) {
            float4 mv = *(const float4*)(&mrow[kb + t * 16 + g * 4]);
            sc[t * 4 + 0] = st[t][0] * 0.125f + mv.x;
            sc[t * 4 + 1] = st[t][1] * 0.125f + mv.y;
            sc[t * 4 + 2] = st[t][2] * 0.125f + mv.z;
            sc[t * 4 + 3] = st[t][3] * 0.125f + mv.w;
        }
        // online softmax for q-col l16: in-lane max of 16, then across g (xor 16,32)
        float vmax = sc[0];
#pragma unroll
        for (int i = 1; i < 16; i++) vmax = fmaxf(vmax, sc[i]);
        vmax = fmaxf(vmax, __shfl_xor(vmax, 16));
        vmax = fmaxf(vmax, __shfl_xor(vmax, 32));
        float mn = fmaxf(m, vmax);
        float alpha = __expf(m - mn);
        m = mn;
        float p[16], rs = 0.f;
#pragma unroll
        for (int i = 0; i < 16; i++) { p[i] = __expf(sc[i] - mn); rs += p[i]; }
        rs += __shfl_xor(rs, 16);
        rs += __shfl_xor(rs, 32);
        l = l * alpha + rs;
        // P^T -> LDS row-major [q=l16][s_local]; packed 4-bf16 writes
#pragma unroll
        for (int t = 0; t < 4; t++) {
            bf16x4 pk = {(bf16)p[t * 4 + 0], (bf16)p[t * 4 + 1],
                         (bf16)p[t * 4 + 2], (bf16)p[t * 4 + 3]};
            *(bf16x4*)(&Pw[l16 * PLD + t * 16 + g * 4]) = pk;
        }
        // rescale O (rows m = g*4+r): fetch alpha of q-row g*4+r from lane g*16+(g*4+r)
        float ar[4];
#pragma unroll
        for (int r = 0; r < 4; r++) ar[r] = __shfl(alpha, g * 4 + r, 16);
#pragma unroll
        for (int nc = 0; nc < 4; nc++)
#pragma unroll
            for (int r = 0; r < 4; r++) o[nc][r] *= ar[r];
        // PV: A-frag P[m=q=l16][k=s=kk*32+g*8+j] from LDS; B-frag V[n=d][k=s] from VT
#pragma unroll
        for (int kk = 0; kk < 2; kk++) {
            bf16x8 pa = *(const bf16x8*)(&Pw[l16 * PLD + kk * 32 + g * 8]);
#pragma unroll
            for (int nc = 0; nc < 4; nc++) {
                bf16x8 vf = *(const bf16x8*)(&Vp[(size_t)(nc * 16 + l16) * 2048 + kb + kk * 32 + g * 8]);
                o[nc] = MFMA(pa, vf, o[nc]);
            }
        }
    }

    // normalize + store vals [4096,1024] bf16; O rows m = g*4+r, cols = nc*16+l16
    int b = bh >> 4, h = bh & 15;
    float lr[4];
#pragma unroll
    for (int r = 0; r < 4; r++) lr[r] = 1.f / __shfl(l, g * 4 + r, 16);
#pragma unroll
    for (int nc = 0; nc < 4; nc++) {
#pragma unroll
        for (int r = 0; r < 4; r++) {
            int row = b * 2048 + qw + g * 4 + r;
            int col = h * 64 + nc * 16 + l16;
            vals[(size_t)row * 1024 + col] = (bf16)(o[nc][r] * lr[r]);
        }
    }
}

// ---------------- GEMM3: vals[4096,1024] @ Wout -> out fp32 ----------------
__global__ __launch_bounds__(256) void gemm_out_kernel(
    const bf16* __restrict__ A, const bf16* __restrict__ BT,
    const float* __restrict__ bias, float* __restrict__ out) {
    const int KDIM = 1024;
    __shared__ bf16 As[128 * LDK];
    __shared__ bf16 Bs[128 * LDK];
    int bm = blockIdx.x, bn = blockIdx.y;
    int t = threadIdx.x;
    int w = t >> 6, lane = t & 63, g = lane >> 4, l16 = lane & 15;
    int wm = (w >> 1) * 64, wn = (w & 1) * 64;
    f32x4 acc[4][4] = {};
    const bf16* Ablk = A + (size_t)(bm * 128) * KDIM;
    const bf16* Bblk = BT + (size_t)(bn * 128) * KDIM;

    for (int kb = 0; kb < KDIM; kb += 32) {
        __syncthreads();
        for (int c = t; c < 512; c += 256) {
            int row = c >> 2, cc = c & 3;
            *(bf16x8*)(&As[row * LDK + cc * 8]) =
                *(const bf16x8*)(&Ablk[(size_t)row * KDIM + kb + cc * 8]);
            *(bf16x8*)(&Bs[row * LDK + cc * 8]) =
                *(const bf16x8*)(&Bblk[(size_t)row * KDIM + kb + cc * 8]);
        }
        __syncthreads();
        bf16x8 af[4], bfr[4];
        for (int mi = 0; mi < 4; mi++)
            af[mi] = *(const bf16x8*)(&As[(wm + mi * 16 + l16) * LDK + g * 8]);
        for (int ni = 0; ni < 4; ni++)
            bfr[ni] = *(const bf16x8*)(&Bs[(wn + ni * 16 + l16) * LDK + g * 8]);
        for (int mi = 0; mi < 4; mi++)
            for (int ni = 0; ni < 4; ni++)
                acc[mi][ni] = MFMA(af[mi], bfr[ni], acc[mi][ni]);
    }

    for (int mi = 0; mi < 4; mi++) {
        for (int ni = 0; ni < 4; ni++) {
            int col = bn * 128 + wn + ni * 16 + l16;
            float bv = bias[col];
            for (int r = 0; r < 4; r++) {
                int row = bm * 128 + wm + mi * 16 + g * 4 + r;
                out[(size_t)row * 1024 + col] = acc[mi][ni][r] + bv;
            }
        }
    }
}

// ---------------- launch ----------------
extern "C" void kernel_launch(void* const* d_in, const int* in_sizes, int n_in,
                              void* d_out, int out_size, void* d_ws, size_t ws_size,
                              hipStream_t stream) {
    const float* x     = (const float*)d_in[0];
    const float* mask  = (const float*)d_in[1];
    const float* w_qkv = (const float*)d_in[2];
    const float* b_qkv = (const float*)d_in[3];
    const float* w_out = (const float*)d_in[4];
    const float* b_out = (const float*)d_in[5];
    float* out = (float*)d_out;

    char* ws = (char*)d_ws;
    size_t off = 0;
    bf16* xb    = (bf16*)(ws + off); off += (size_t)4096 * 1024 * 2;
    bf16* wqkvT = (bf16*)(ws + off); off += (size_t)3072 * 1024 * 2;
    bf16* woutT = (bf16*)(ws + off); off += (size_t)1024 * 1024 * 2;
    bf16* Qa    = (bf16*)(ws + off); off += (size_t)32 * 2048 * 64 * 2;
    bf16* Ka    = (bf16*)(ws + off); off += (size_t)32 * 2048 * 64 * 2;
    bf16* VTa   = (bf16*)(ws + off); off += (size_t)32 * 64 * 2048 * 2;
    bf16* vals  = (bf16*)(ws + off); off += (size_t)4096 * 1024 * 2;

    cast4_kernel<<<4096, 256, 0, stream>>>(x, xb, 4096 * 1024 / 4);
    transpose_cast_kernel<<<dim3(96, 32), dim3(32, 8), 0, stream>>>(w_qkv, wqkvT, 1024, 3072);
    transpose_cast_kernel<<<dim3(32, 32), dim3(32, 8), 0, stream>>>(w_out, woutT, 1024, 1024);
    gemm_qkv_kernel<<<dim3(32, 24), 256, 0, stream>>>(xb, wqkvT, b_qkv, Qa, Ka, VTa);
    attn_kernel<<<1024, 256, 0, stream>>>(Qa, Ka, VTa, mask, vals);
    gemm_out_kernel<<<dim3(32, 8), 256, 0, stream>>>(vals, woutT, b_out, out);
}

// Round 5
// 267.514 us; speedup vs baseline: 1.6934x; 1.6934x over previous
//
#include <hip/hip_runtime.h>

// MHA: B=2, S=2048, D=1024, H=16, hd=64. fp32 in/out, bf16 MFMA internally.
// R4: fix R3's prologue race — compiler may reorder prologue loads (no asm
// barrier there), breaking the vmcnt(8) accounting for tiles 0/1. Add ONE
// full vmcnt(0) drain + s_barrier after the prologue; in-loop vmcnt(8) math
// is then exact for all iterations (4 vmem ops per asm-delimited segment).

typedef __bf16 bf16;
typedef __bf16 bf16x2 __attribute__((ext_vector_type(2)));
typedef __bf16 bf16x4 __attribute__((ext_vector_type(4)));
typedef __bf16 bf16x8 __attribute__((ext_vector_type(8)));
typedef float f32x4 __attribute__((ext_vector_type(4)));

#define MFMA(a, b, c) __builtin_amdgcn_mfma_f32_16x16x32_bf16((a), (b), (c), 0, 0, 0)

#if __has_builtin(__builtin_amdgcn_exp2f)
#define EXP2(x) __builtin_amdgcn_exp2f(x)
#else
#define EXP2(x) exp2f(x)
#endif

__device__ __forceinline__ void load_lds16(const bf16* g, void* l) {
    __builtin_amdgcn_global_load_lds(
        (const __attribute__((address_space(1))) unsigned int*)g,
        (__attribute__((address_space(3))) unsigned int*)l, 16, 0, 0);
}

// ---------------- cast fp32 -> bf16, 4 elems/thread ----------------
__global__ void cast4_kernel(const float* __restrict__ in, bf16* __restrict__ out, int n4) {
    int i = blockIdx.x * blockDim.x + threadIdx.x;
    if (i < n4) {
        float4 v = ((const float4*)in)[i];
        bf16x4 o = {(bf16)v.x, (bf16)v.y, (bf16)v.z, (bf16)v.w};
        ((bf16x4*)out)[i] = o;
    }
}

// ---------------- transpose + cast: in [R,C] fp32 -> out [C,R] bf16 ----------------
__global__ void transpose_cast_kernel(const float* __restrict__ in, bf16* __restrict__ out,
                                      int R, int C) {
    __shared__ float tile[32][33];
    int bx = blockIdx.x * 32;
    int by = blockIdx.y * 32;
    int tx = threadIdx.x, ty = threadIdx.y;  // (32,8)
    for (int i = 0; i < 32; i += 8)
        tile[ty + i][tx] = in[(size_t)(by + ty + i) * C + bx + tx];
    __syncthreads();
    for (int i = 0; i < 32; i += 8)
        out[(size_t)(bx + ty + i) * R + by + tx] = (bf16)tile[tx][ty + i];
}

// ---------------- GEMM1: X[4096,1024] @ Wqkv -> scatter Q,K,VT (bf16) ----------------
#define LDK 40

__global__ __launch_bounds__(256) void gemm_qkv_kernel(
    const bf16* __restrict__ A, const bf16* __restrict__ BT,
    const float* __restrict__ bias,
    bf16* __restrict__ Q, bf16* __restrict__ K, bf16* __restrict__ VT) {
    const int KDIM = 1024;
    __shared__ bf16 As[128 * LDK];
    __shared__ bf16 Bs[128 * LDK];
    int bm = blockIdx.x, bn = blockIdx.y;
    int t = threadIdx.x;
    int w = t >> 6, lane = t & 63, g = lane >> 4, l16 = lane & 15;
    int wm = (w >> 1) * 64, wn = (w & 1) * 64;
    f32x4 acc[4][4] = {};
    const bf16* Ablk = A + (size_t)(bm * 128) * KDIM;
    const bf16* Bblk = BT + (size_t)(bn * 128) * KDIM;

    for (int kb = 0; kb < KDIM; kb += 32) {
        __syncthreads();
        for (int c = t; c < 512; c += 256) {
            int row = c >> 2, cc = c & 3;
            *(bf16x8*)(&As[row * LDK + cc * 8]) =
                *(const bf16x8*)(&Ablk[(size_t)row * KDIM + kb + cc * 8]);
            *(bf16x8*)(&Bs[row * LDK + cc * 8]) =
                *(const bf16x8*)(&Bblk[(size_t)row * KDIM + kb + cc * 8]);
        }
        __syncthreads();
        bf16x8 af[4], bfr[4];
        for (int mi = 0; mi < 4; mi++)
            af[mi] = *(const bf16x8*)(&As[(wm + mi * 16 + l16) * LDK + g * 8]);
        for (int ni = 0; ni < 4; ni++)
            bfr[ni] = *(const bf16x8*)(&Bs[(wn + ni * 16 + l16) * LDK + g * 8]);
        for (int mi = 0; mi < 4; mi++)
            for (int ni = 0; ni < 4; ni++)
                acc[mi][ni] = MFMA(af[mi], bfr[ni], acc[mi][ni]);
    }

    for (int mi = 0; mi < 4; mi++) {
        for (int ni = 0; ni < 4; ni++) {
            int col = bn * 128 + wn + ni * 16 + l16;
            float bv = bias[col];
            int h = col / 192, tt = col % 192;
            for (int r = 0; r < 4; r++) {
                int row = bm * 128 + wm + mi * 16 + g * 4 + r;
                float v = acc[mi][ni][r] + bv;
                int b = row >> 11, s = row & 2047;
                size_t bh = (size_t)(b * 16 + h);
                if (tt < 64)
                    Q[(bh * 2048 + s) * 64 + tt] = (bf16)v;
                else if (tt < 128)
                    K[(bh * 2048 + s) * 64 + (tt - 64)] = (bf16)v;
                else
                    VT[(bh * 64 + (tt - 128)) * 2048 + s] = (bf16)v;
            }
        }
    }
}

// ---------------- flash attention (R4) ----------------
// grid = 1024, block = 256 (4 waves x 16 q-rows). BK=32 per iteration, 64 iters.
// bh = (blk&7)*4 + ((blk>>3)&3): XCD x serves bh {4x..4x+3} -> 2 MB K/V per L2.
// LDS: 4 buffers x (K 4KB + V 4KB), staged via global_load_lds w=16, distance-2
// prefetch. Prologue: FULL vmcnt(0) drain + barrier (tiles 0/1 safe regardless
// of compiler scheduling). In-loop: s_waitcnt vmcnt(8) + raw s_barrier.
__global__ __launch_bounds__(256, 4) void attn_kernel(
    const bf16* __restrict__ Q, const bf16* __restrict__ K,
    const bf16* __restrict__ VT, const float* __restrict__ mask,
    bf16* __restrict__ vals) {
    __shared__ __attribute__((aligned(16))) char lds[4][8192];  // [buf]: K[0,4K) V[4K,8K)

    int blk = blockIdx.x;
    int bh = ((blk & 7) << 2) | ((blk >> 3) & 3);
    int qt = blk >> 5;
    int t = threadIdx.x;
    int w = t >> 6, lane = t & 63, g = lane >> 4, l16 = lane & 15;
    int qw = qt * 64 + w * 16;

    const bf16* Qp = Q + (size_t)bh * 2048 * 64;
    const bf16* Kp = K + (size_t)bh * 2048 * 64;
    const bf16* Vp = VT + (size_t)bh * 64 * 2048;
    const float* mrow = mask + (size_t)(qw + l16) * 2048;

    // staging constants (thread t stages 16B slot t of K region and of V region)
    int ks_row = t >> 3;                       // s_local 0..31
    int ks_cblk = (t & 7) ^ (ks_row & 7);      // XOR swizzle
    const bf16* kg = Kp + ks_row * 64 + ks_cblk * 8;   // + kb*64 per tile
    int vs_d = t >> 2;                         // d 0..63
    int vs_sblk = (t & 3) ^ ((t >> 3) & 3);
    const bf16* vg = Vp + (size_t)vs_d * 2048 + vs_sblk * 8;  // + kb per tile

    const float SCL = 0.125f * 1.44269504089f;  // 1/sqrt(64) * log2(e)
    const float L2E = 1.44269504089f;

    // ---- prologue: issue everything, then FULL drain + barrier ----
    bf16x8 q0 = *(const bf16x8*)(&Qp[(size_t)(qw + l16) * 64 + g * 8]);
    bf16x8 q1 = *(const bf16x8*)(&Qp[(size_t)(qw + l16) * 64 + 32 + g * 8]);
    load_lds16(kg + 0, &lds[0][t * 16]);
    load_lds16(vg + 0, &lds[0][4096 + t * 16]);
    float4 mv0 = *(const float4*)(&mrow[0 + g * 4]);
    float4 mv1 = *(const float4*)(&mrow[16 + g * 4]);
    load_lds16(kg + 1 * 32 * 64, &lds[1][t * 16]);
    load_lds16(vg + 1 * 32, &lds[1][4096 + t * 16]);
    asm volatile("s_waitcnt vmcnt(0)" ::: "memory");
    asm volatile("s_barrier" ::: "memory");

    f32x4 o[4] = {};
    float m = -1e30f, l = 0.f;  // per-lane state for q-col l16 (replicated over g)

    for (int j = 0; j < 64; j++) {
        int buf = j & 3;
        // segment j: exactly 4 vmem ops between the asm clobber boundaries
        int jm = j + 1 < 64 ? j + 1 : 63;
        float4 nmv0 = *(const float4*)(&mrow[jm * 32 + g * 4]);
        float4 nmv1 = *(const float4*)(&mrow[jm * 32 + 16 + g * 4]);
        int jp = j + 2 < 64 ? j + 2 : 63;
        load_lds16(kg + (size_t)jp * 32 * 64, &lds[(j + 2) & 3][t * 16]);
        load_lds16(vg + jp * 32, &lds[(j + 2) & 3][4096 + t * 16]);
        // drain all but segments j-1 and j (8 loads) -> tile j's staging landed
        asm volatile("s_waitcnt vmcnt(8)" ::: "memory");
        asm volatile("s_barrier" ::: "memory");

        // ---- S^T = K·Q^T on tile j: lane holds S^T[s=ts*16+g*4+r][q=l16] ----
        float sc[8];
#pragma unroll
        for (int ts = 0; ts < 2; ts++) {
            int s0 = ts * 16 + l16;
            int sw = s0 & 7;
            bf16x8 k0 = *(const bf16x8*)(&lds[buf][(s0 * 8 + (g ^ sw)) * 16]);
            bf16x8 k1 = *(const bf16x8*)(&lds[buf][(s0 * 8 + ((4 + g) ^ sw)) * 16]);
            f32x4 st = {};
            st = MFMA(k0, q0, st);
            st = MFMA(k1, q1, st);
            float4 mv = ts ? *(float4*)&mv1 : *(float4*)&mv0;
            sc[ts * 4 + 0] = st[0] * SCL + mv.x * L2E;
            sc[ts * 4 + 1] = st[1] * SCL + mv.y * L2E;
            sc[ts * 4 + 2] = st[2] * SCL + mv.z * L2E;
            sc[ts * 4 + 3] = st[3] * SCL + mv.w * L2E;
        }

        // ---- online softmax (log2 domain), state per-lane for q=l16 ----
        float vmax = sc[0];
#pragma unroll
        for (int i = 1; i < 8; i++) vmax = fmaxf(vmax, sc[i]);
        vmax = fmaxf(vmax, __shfl_xor(vmax, 16, 64));
        vmax = fmaxf(vmax, __shfl_xor(vmax, 32, 64));
        float mn = fmaxf(m, vmax);
        float alpha = EXP2(m - mn);
        m = mn;
        float p[8], rs = 0.f;
#pragma unroll
        for (int i = 0; i < 8; i++) { p[i] = EXP2(sc[i] - mn); rs += p[i]; }
        rs += __shfl_xor(rs, 16, 64);
        rs += __shfl_xor(rs, 32, 64);
        l = l * alpha + rs;
#pragma unroll
        for (int nc = 0; nc < 4; nc++) {
            o[nc][0] *= alpha; o[nc][1] *= alpha; o[nc][2] *= alpha; o[nc][3] *= alpha;
        }

        // ---- P: C-layout -> B-frag via shfl (no LDS round-trip) ----
        // Lane (g,l16) holds P[s=ts*16+g*4+r][q=l16] in p[ts*4+r] (ts=0,1).
        // B-frag dword j2 of dest lane (g,l16) needs P[s=8g+2*j2+{0,1}][q=l16]:
        //   ts_needed = g>>1 (DESTINATION property), source g' = (2g+(j2>>1))&3,
        //   r = 2*(j2&1)+{0,1}. Shuffle both ts candidates, select by dest g&2.
        int dw0, dw1, dw2, dw3;
        { union { bf16x2 h; int i; } u;
          u.h = bf16x2{(bf16)p[0], (bf16)p[1]}; dw0 = u.i;   // ts0 r01
          u.h = bf16x2{(bf16)p[2], (bf16)p[3]}; dw1 = u.i;   // ts0 r23
          u.h = bf16x2{(bf16)p[4], (bf16)p[5]}; dw2 = u.i;   // ts1 r01
          u.h = bf16x2{(bf16)p[6], (bf16)p[7]}; dw3 = u.i; } // ts1 r23
        int selA = (((2 * g) & 3) << 4) | l16;
        int selB = (((2 * g + 1) & 3) << 4) | l16;
        int t0a = __shfl(dw0, selA, 64), t2a = __shfl(dw2, selA, 64);
        int t1a = __shfl(dw1, selA, 64), t3a = __shfl(dw3, selA, 64);
        int t0b = __shfl(dw0, selB, 64), t2b = __shfl(dw2, selB, 64);
        int t1b = __shfl(dw1, selB, 64), t3b = __shfl(dw3, selB, 64);
        bool hi = (g & 2) != 0;  // destination ts
        union { int i[4]; bf16x8 v; } pu;
        pu.i[0] = hi ? t2a : t0a;
        pu.i[1] = hi ? t3a : t1a;
        pu.i[2] = hi ? t2b : t0b;
        pu.i[3] = hi ? t3b : t1b;

        // ---- O^T += V^T · P : A-frag = V^T[d=nc*16+l16][s=g*8+j] from LDS ----
#pragma unroll
        for (int nc = 0; nc < 4; nc++) {
            int d = nc * 16 + l16;
            int slot = d * 4 + (g ^ ((d >> 1) & 3));
            bf16x8 vf = *(const bf16x8*)(&lds[buf][4096 + slot * 16]);
            o[nc] = MFMA(vf, pu.v, o[nc]);
        }

        mv0 = nmv0;
        mv1 = nmv1;
    }

    // ---- epilogue: O^T[d][q] -> vals[row=q][col=h*64+d], per-lane 1/l ----
    int b = bh >> 4, h = bh & 15;
    float linv = 1.f / l;
    size_t row = (size_t)(b * 2048 + qw + l16);
#pragma unroll
    for (int nc = 0; nc < 4; nc++) {
        bf16x4 pk = {(bf16)(o[nc][0] * linv), (bf16)(o[nc][1] * linv),
                     (bf16)(o[nc][2] * linv), (bf16)(o[nc][3] * linv)};
        *(bf16x4*)(&vals[row * 1024 + h * 64 + nc * 16 + g * 4]) = pk;
    }
}

// ---------------- GEMM3: vals[4096,1024] @ Wout -> out fp32 ----------------
__global__ __launch_bounds__(256) void gemm_out_kernel(
    const bf16* __restrict__ A, const bf16* __restrict__ BT,
    const float* __restrict__ bias, float* __restrict__ out) {
    const int KDIM = 1024;
    __shared__ bf16 As[128 * LDK];
    __shared__ bf16 Bs[128 * LDK];
    int bm = blockIdx.x, bn = blockIdx.y;
    int t = threadIdx.x;
    int w = t >> 6, lane = t & 63, g = lane >> 4, l16 = lane & 15;
    int wm = (w >> 1) * 64, wn = (w & 1) * 64;
    f32x4 acc[4][4] = {};
    const bf16* Ablk = A + (size_t)(bm * 128) * KDIM;
    const bf16* Bblk = BT + (size_t)(bn * 128) * KDIM;

    for (int kb = 0; kb < KDIM; kb += 32) {
        __syncthreads();
        for (int c = t; c < 512; c += 256) {
            int row = c >> 2, cc = c & 3;
            *(bf16x8*)(&As[row * LDK + cc * 8]) =
                *(const bf16x8*)(&Ablk[(size_t)row * KDIM + kb + cc * 8]);
            *(bf16x8*)(&Bs[row * LDK + cc * 8]) =
                *(const bf16x8*)(&Bblk[(size_t)row * KDIM + kb + cc * 8]);
        }
        __syncthreads();
        bf16x8 af[4], bfr[4];
        for (int mi = 0; mi < 4; mi++)
            af[mi] = *(const bf16x8*)(&As[(wm + mi * 16 + l16) * LDK + g * 8]);
        for (int ni = 0; ni < 4; ni++)
            bfr[ni] = *(const bf16x8*)(&Bs[(wn + ni * 16 + l16) * LDK + g * 8]);
        for (int mi = 0; mi < 4; mi++)
            for (int ni = 0; ni < 4; ni++)
                acc[mi][ni] = MFMA(af[mi], bfr[ni], acc[mi][ni]);
    }

    for (int mi = 0; mi < 4; mi++) {
        for (int ni = 0; ni < 4; ni++) {
            int col = bn * 128 + wn + ni * 16 + l16;
            float bv = bias[col];
            for (int r = 0; r < 4; r++) {
                int row = bm * 128 + wm + mi * 16 + g * 4 + r;
                out[(size_t)row * 1024 + col] = acc[mi][ni][r] + bv;
            }
        }
    }
}

// ---------------- launch ----------------
extern "C" void kernel_launch(void* const* d_in, const int* in_sizes, int n_in,
                              void* d_out, int out_size, void* d_ws, size_t ws_size,
                              hipStream_t stream) {
    const float* x     = (const float*)d_in[0];
    const float* mask  = (const float*)d_in[1];
    const float* w_qkv = (const float*)d_in[2];
    const float* b_qkv = (const float*)d_in[3];
    const float* w_out = (const float*)d_in[4];
    const float* b_out = (const float*)d_in[5];
    float* out = (float*)d_out;

    char* ws = (char*)d_ws;
    size_t off = 0;
    bf16* xb    = (bf16*)(ws + off); off += (size_t)4096 * 1024 * 2;
    bf16* wqkvT = (bf16*)(ws + off); off += (size_t)3072 * 1024 * 2;
    bf16* woutT = (bf16*)(ws + off); off += (size_t)1024 * 1024 * 2;
    bf16* Qa    = (bf16*)(ws + off); off += (size_t)32 * 2048 * 64 * 2;
    bf16* Ka    = (bf16*)(ws + off); off += (size_t)32 * 2048 * 64 * 2;
    bf16* VTa   = (bf16*)(ws + off); off += (size_t)32 * 64 * 2048 * 2;
    bf16* vals  = (bf16*)(ws + off); off += (size_t)4096 * 1024 * 2;

    cast4_kernel<<<4096, 256, 0, stream>>>(x, xb, 4096 * 1024 / 4);
    transpose_cast_kernel<<<dim3(96, 32), dim3(32, 8), 0, stream>>>(w_qkv, wqkvT, 1024, 3072);
    transpose_cast_kernel<<<dim3(32, 32), dim3(32, 8), 0, stream>>>(w_out, woutT, 1024, 1024);
    gemm_qkv_kernel<<<dim3(32, 24), 256, 0, stream>>>(xb, wqkvT, b_qkv, Qa, Ka, VTa);
    attn_kernel<<<1024, 256, 0, stream>>>(Qa, Ka, VTa, mask, vals);
    gemm_out_kernel<<<dim3(32, 8), 256, 0, stream>>>(vals, woutT, b_out, out);
}

// Round 6
// 248.733 us; speedup vs baseline: 1.8213x; 1.0755x over previous
//
#include <hip/hip_runtime.h>

// MHA: B=2, S=2048, D=1024, H=16, hd=64. fp32 in/out, bf16 MFMA internally.
// R5: m97-style GEMMs — global_load_lds(16B) staging with SOURCE-side XOR
// swizzle (LDS dest forced to lane*16), single-buffer 2-barrier K-loop,
// bf16x4-packed V^T epilogue stores. Attn unchanged from R4 (110.9 us).

typedef __bf16 bf16;
typedef __bf16 bf16x2 __attribute__((ext_vector_type(2)));
typedef __bf16 bf16x4 __attribute__((ext_vector_type(4)));
typedef __bf16 bf16x8 __attribute__((ext_vector_type(8)));
typedef float f32x4 __attribute__((ext_vector_type(4)));

#define MFMA(a, b, c) __builtin_amdgcn_mfma_f32_16x16x32_bf16((a), (b), (c), 0, 0, 0)

#if __has_builtin(__builtin_amdgcn_exp2f)
#define EXP2(x) __builtin_amdgcn_exp2f(x)
#else
#define EXP2(x) exp2f(x)
#endif

__device__ __forceinline__ void load_lds16(const bf16* g, void* l) {
    __builtin_amdgcn_global_load_lds(
        (const __attribute__((address_space(1))) unsigned int*)g,
        (__attribute__((address_space(3))) unsigned int*)l, 16, 0, 0);
}

// ---------------- cast fp32 -> bf16, 4 elems/thread ----------------
__global__ void cast4_kernel(const float* __restrict__ in, bf16* __restrict__ out, int n4) {
    int i = blockIdx.x * blockDim.x + threadIdx.x;
    if (i < n4) {
        float4 v = ((const float4*)in)[i];
        bf16x4 o = {(bf16)v.x, (bf16)v.y, (bf16)v.z, (bf16)v.w};
        ((bf16x4*)out)[i] = o;
    }
}

// ---------------- transpose + cast: in [R,C] fp32 -> out [C,R] bf16 ----------------
__global__ void transpose_cast_kernel(const float* __restrict__ in, bf16* __restrict__ out,
                                      int R, int C) {
    __shared__ float tile[32][33];
    int bx = blockIdx.x * 32;
    int by = blockIdx.y * 32;
    int tx = threadIdx.x, ty = threadIdx.y;  // (32,8)
    for (int i = 0; i < 32; i += 8)
        tile[ty + i][tx] = in[(size_t)(by + ty + i) * C + bx + tx];
    __syncthreads();
    for (int i = 0; i < 32; i += 8)
        out[(size_t)(bx + ty + i) * R + by + tx] = (bf16)tile[tx][ty + i];
}

// ================= m97-style GEMM core (128x128 tile, BK=32) =================
// LDS layout (no pad; global_load_lds forces dst = lane*16): As[row*32 + cc*8]
// where slot cc holds GLOBAL chunk cc^(row&3) (source-side XOR swizzle).
// Fragment read for global chunk g of row: LDS chunk g^(row&3).
// Staging: thread t covers rows t>>2 and 64+(t>>2), slot t&3, 4 load_lds/step.

#define GEMM_PROLOG(KDIM)                                                        \
    __shared__ __attribute__((aligned(16))) bf16 As[128 * 32];                   \
    __shared__ __attribute__((aligned(16))) bf16 Bs[128 * 32];                   \
    int bm = blockIdx.x, bn = blockIdx.y;                                        \
    int t = threadIdx.x;                                                         \
    int w = t >> 6, lane = t & 63, g = lane >> 4, l16 = lane & 15;               \
    int wm = (w >> 1) * 64, wn = (w & 1) * 64;                                   \
    f32x4 acc[4][4] = {};                                                        \
    const bf16* Ablk = A + (size_t)(bm * 128) * KDIM;                            \
    const bf16* Bblk = BT + (size_t)(bn * 128) * KDIM;                           \
    int srow = t >> 2;                                                           \
    int scg = (t & 3) ^ (srow & 3); /* global chunk for this lane's slot */      \
    const bf16* ag0 = Ablk + (size_t)srow * KDIM + scg * 8;                      \
    const bf16* ag1 = Ablk + (size_t)(srow + 64) * KDIM + scg * 8;               \
    const bf16* bg0 = Bblk + (size_t)srow * KDIM + scg * 8;                      \
    const bf16* bg1 = Bblk + (size_t)(srow + 64) * KDIM + scg * 8;               \
    char* asl = (char*)As;                                                       \
    char* bsl = (char*)Bs;                                                       \
    for (int kb = 0; kb < KDIM; kb += 32) {                                      \
        __syncthreads();                                                         \
        load_lds16(ag0 + kb, asl + t * 16);                                      \
        load_lds16(ag1 + kb, asl + 4096 + t * 16);                               \
        load_lds16(bg0 + kb, bsl + t * 16);                                      \
        load_lds16(bg1 + kb, bsl + 4096 + t * 16);                               \
        __syncthreads();                                                         \
        bf16x8 af[4], bfr[4];                                                    \
        int sw = l16 & 3;                                                        \
        for (int mi = 0; mi < 4; mi++) {                                         \
            int row = wm + mi * 16 + l16;                                        \
            af[mi] = *(const bf16x8*)(&As[row * 32 + (g ^ sw) * 8]);             \
        }                                                                        \
        for (int ni = 0; ni < 4; ni++) {                                         \
            int row = wn + ni * 16 + l16;                                        \
            bfr[ni] = *(const bf16x8*)(&Bs[row * 32 + (g ^ sw) * 8]);            \
        }                                                                        \
        for (int mi = 0; mi < 4; mi++)                                           \
            for (int ni = 0; ni < 4; ni++)                                       \
                acc[mi][ni] = MFMA(af[mi], bfr[ni], acc[mi][ni]);                \
    }

// ---------------- GEMM1: X[4096,1024] @ Wqkv -> scatter Q,K,VT (bf16) ----------------
__global__ __launch_bounds__(256) void gemm_qkv_kernel(
    const bf16* __restrict__ A, const bf16* __restrict__ BT,
    const float* __restrict__ bias,
    bf16* __restrict__ Q, bf16* __restrict__ K, bf16* __restrict__ VT) {
    GEMM_PROLOG(1024)

    // epilogue: scatter to Q [bh,s,d], K [bh,s,d], VT [bh,d,s]
    for (int mi = 0; mi < 4; mi++) {
        int row0 = bm * 128 + wm + mi * 16 + g * 4;  // 4 consecutive rows
        int b = row0 >> 11, s0 = row0 & 2047;
        for (int ni = 0; ni < 4; ni++) {
            int col = bn * 128 + wn + ni * 16 + l16;  // 0..3071
            float bv = bias[col];
            int h = col / 192, tt = col % 192;
            size_t bh = (size_t)(b * 16 + h);
            if (tt < 128) {
                bf16* dst = (tt < 64) ? &Q[(bh * 2048 + s0) * 64 + tt]
                                      : &K[(bh * 2048 + s0) * 64 + (tt - 64)];
                for (int r = 0; r < 4; r++)
                    dst[(size_t)r * 64] = (bf16)(acc[mi][ni][r] + bv);
            } else {
                // VT[bh][d][s]: r = 4 consecutive s -> one packed 8B store
                bf16x4 pk = {(bf16)(acc[mi][ni][0] + bv), (bf16)(acc[mi][ni][1] + bv),
                             (bf16)(acc[mi][ni][2] + bv), (bf16)(acc[mi][ni][3] + bv)};
                *(bf16x4*)(&VT[(bh * 64 + (tt - 128)) * 2048 + s0]) = pk;
            }
        }
    }
}

// ---------------- GEMM3: vals[4096,1024] @ Wout -> out fp32 ----------------
__global__ __launch_bounds__(256) void gemm_out_kernel(
    const bf16* __restrict__ A, const bf16* __restrict__ BT,
    const float* __restrict__ bias, float* __restrict__ out) {
    GEMM_PROLOG(1024)

    for (int mi = 0; mi < 4; mi++) {
        for (int ni = 0; ni < 4; ni++) {
            int col = bn * 128 + wn + ni * 16 + l16;
            float bv = bias[col];
            for (int r = 0; r < 4; r++) {
                int row = bm * 128 + wm + mi * 16 + g * 4 + r;
                out[(size_t)row * 1024 + col] = acc[mi][ni][r] + bv;
            }
        }
    }
}

// ---------------- flash attention (R4, unchanged) ----------------
// grid = 1024, block = 256 (4 waves x 16 q-rows). BK=32 per iteration, 64 iters.
// bh = (blk&7)*4 + ((blk>>3)&3): XCD x serves bh {4x..4x+3} -> 2 MB K/V per L2.
// LDS: 4 buffers x (K 4KB + V 4KB), staged via global_load_lds w=16, distance-2
// prefetch. Prologue: FULL vmcnt(0) drain + barrier. In-loop: vmcnt(8) + s_barrier.
__global__ __launch_bounds__(256, 4) void attn_kernel(
    const bf16* __restrict__ Q, const bf16* __restrict__ K,
    const bf16* __restrict__ VT, const float* __restrict__ mask,
    bf16* __restrict__ vals) {
    __shared__ __attribute__((aligned(16))) char lds[4][8192];  // [buf]: K[0,4K) V[4K,8K)

    int blk = blockIdx.x;
    int bh = ((blk & 7) << 2) | ((blk >> 3) & 3);
    int qt = blk >> 5;
    int t = threadIdx.x;
    int w = t >> 6, lane = t & 63, g = lane >> 4, l16 = lane & 15;
    int qw = qt * 64 + w * 16;

    const bf16* Qp = Q + (size_t)bh * 2048 * 64;
    const bf16* Kp = K + (size_t)bh * 2048 * 64;
    const bf16* Vp = VT + (size_t)bh * 64 * 2048;
    const float* mrow = mask + (size_t)(qw + l16) * 2048;

    int ks_row = t >> 3;                       // s_local 0..31
    int ks_cblk = (t & 7) ^ (ks_row & 7);      // XOR swizzle
    const bf16* kg = Kp + ks_row * 64 + ks_cblk * 8;
    int vs_d = t >> 2;                         // d 0..63
    int vs_sblk = (t & 3) ^ ((t >> 3) & 3);
    const bf16* vg = Vp + (size_t)vs_d * 2048 + vs_sblk * 8;

    const float SCL = 0.125f * 1.44269504089f;
    const float L2E = 1.44269504089f;

    bf16x8 q0 = *(const bf16x8*)(&Qp[(size_t)(qw + l16) * 64 + g * 8]);
    bf16x8 q1 = *(const bf16x8*)(&Qp[(size_t)(qw + l16) * 64 + 32 + g * 8]);
    load_lds16(kg + 0, &lds[0][t * 16]);
    load_lds16(vg + 0, &lds[0][4096 + t * 16]);
    float4 mv0 = *(const float4*)(&mrow[0 + g * 4]);
    float4 mv1 = *(const float4*)(&mrow[16 + g * 4]);
    load_lds16(kg + 1 * 32 * 64, &lds[1][t * 16]);
    load_lds16(vg + 1 * 32, &lds[1][4096 + t * 16]);
    asm volatile("s_waitcnt vmcnt(0)" ::: "memory");
    asm volatile("s_barrier" ::: "memory");

    f32x4 o[4] = {};
    float m = -1e30f, l = 0.f;

    for (int j = 0; j < 64; j++) {
        int buf = j & 3;
        int jm = j + 1 < 64 ? j + 1 : 63;
        float4 nmv0 = *(const float4*)(&mrow[jm * 32 + g * 4]);
        float4 nmv1 = *(const float4*)(&mrow[jm * 32 + 16 + g * 4]);
        int jp = j + 2 < 64 ? j + 2 : 63;
        load_lds16(kg + (size_t)jp * 32 * 64, &lds[(j + 2) & 3][t * 16]);
        load_lds16(vg + jp * 32, &lds[(j + 2) & 3][4096 + t * 16]);
        asm volatile("s_waitcnt vmcnt(8)" ::: "memory");
        asm volatile("s_barrier" ::: "memory");

        float sc[8];
#pragma unroll
        for (int ts = 0; ts < 2; ts++) {
            int s0 = ts * 16 + l16;
            int sw = s0 & 7;
            bf16x8 k0 = *(const bf16x8*)(&lds[buf][(s0 * 8 + (g ^ sw)) * 16]);
            bf16x8 k1 = *(const bf16x8*)(&lds[buf][(s0 * 8 + ((4 + g) ^ sw)) * 16]);
            f32x4 st = {};
            st = MFMA(k0, q0, st);
            st = MFMA(k1, q1, st);
            float4 mv = ts ? *(float4*)&mv1 : *(float4*)&mv0;
            sc[ts * 4 + 0] = st[0] * SCL + mv.x * L2E;
            sc[ts * 4 + 1] = st[1] * SCL + mv.y * L2E;
            sc[ts * 4 + 2] = st[2] * SCL + mv.z * L2E;
            sc[ts * 4 + 3] = st[3] * SCL + mv.w * L2E;
        }

        float vmax = sc[0];
#pragma unroll
        for (int i = 1; i < 8; i++) vmax = fmaxf(vmax, sc[i]);
        vmax = fmaxf(vmax, __shfl_xor(vmax, 16, 64));
        vmax = fmaxf(vmax, __shfl_xor(vmax, 32, 64));
        float mn = fmaxf(m, vmax);
        float alpha = EXP2(m - mn);
        m = mn;
        float p[8], rs = 0.f;
#pragma unroll
        for (int i = 0; i < 8; i++) { p[i] = EXP2(sc[i] - mn); rs += p[i]; }
        rs += __shfl_xor(rs, 16, 64);
        rs += __shfl_xor(rs, 32, 64);
        l = l * alpha + rs;
#pragma unroll
        for (int nc = 0; nc < 4; nc++) {
            o[nc][0] *= alpha; o[nc][1] *= alpha; o[nc][2] *= alpha; o[nc][3] *= alpha;
        }

        int dw0, dw1, dw2, dw3;
        { union { bf16x2 h; int i; } u;
          u.h = bf16x2{(bf16)p[0], (bf16)p[1]}; dw0 = u.i;
          u.h = bf16x2{(bf16)p[2], (bf16)p[3]}; dw1 = u.i;
          u.h = bf16x2{(bf16)p[4], (bf16)p[5]}; dw2 = u.i;
          u.h = bf16x2{(bf16)p[6], (bf16)p[7]}; dw3 = u.i; }
        int selA = (((2 * g) & 3) << 4) | l16;
        int selB = (((2 * g + 1) & 3) << 4) | l16;
        int t0a = __shfl(dw0, selA, 64), t2a = __shfl(dw2, selA, 64);
        int t1a = __shfl(dw1, selA, 64), t3a = __shfl(dw3, selA, 64);
        int t0b = __shfl(dw0, selB, 64), t2b = __shfl(dw2, selB, 64);
        int t1b = __shfl(dw1, selB, 64), t3b = __shfl(dw3, selB, 64);
        bool hi = (g & 2) != 0;
        union { int i[4]; bf16x8 v; } pu;
        pu.i[0] = hi ? t2a : t0a;
        pu.i[1] = hi ? t3a : t1a;
        pu.i[2] = hi ? t2b : t0b;
        pu.i[3] = hi ? t3b : t1b;

#pragma unroll
        for (int nc = 0; nc < 4; nc++) {
            int d = nc * 16 + l16;
            int slot = d * 4 + (g ^ ((d >> 1) & 3));
            bf16x8 vf = *(const bf16x8*)(&lds[buf][4096 + slot * 16]);
            o[nc] = MFMA(vf, pu.v, o[nc]);
        }

        mv0 = nmv0;
        mv1 = nmv1;
    }

    int b = bh >> 4, h = bh & 15;
    float linv = 1.f / l;
    size_t row = (size_t)(b * 2048 + qw + l16);
#pragma unroll
    for (int nc = 0; nc < 4; nc++) {
        bf16x4 pk = {(bf16)(o[nc][0] * linv), (bf16)(o[nc][1] * linv),
                     (bf16)(o[nc][2] * linv), (bf16)(o[nc][3] * linv)};
        *(bf16x4*)(&vals[row * 1024 + h * 64 + nc * 16 + g * 4]) = pk;
    }
}

// ---------------- launch ----------------
extern "C" void kernel_launch(void* const* d_in, const int* in_sizes, int n_in,
                              void* d_out, int out_size, void* d_ws, size_t ws_size,
                              hipStream_t stream) {
    const float* x     = (const float*)d_in[0];
    const float* mask  = (const float*)d_in[1];
    const float* w_qkv = (const float*)d_in[2];
    const float* b_qkv = (const float*)d_in[3];
    const float* w_out = (const float*)d_in[4];
    const float* b_out = (const float*)d_in[5];
    float* out = (float*)d_out;

    char* ws = (char*)d_ws;
    size_t off = 0;
    bf16* xb    = (bf16*)(ws + off); off += (size_t)4096 * 1024 * 2;
    bf16* wqkvT = (bf16*)(ws + off); off += (size_t)3072 * 1024 * 2;
    bf16* woutT = (bf16*)(ws + off); off += (size_t)1024 * 1024 * 2;
    bf16* Qa    = (bf16*)(ws + off); off += (size_t)32 * 2048 * 64 * 2;
    bf16* Ka    = (bf16*)(ws + off); off += (size_t)32 * 2048 * 64 * 2;
    bf16* VTa   = (bf16*)(ws + off); off += (size_t)32 * 64 * 2048 * 2;
    bf16* vals  = (bf16*)(ws + off); off += (size_t)4096 * 1024 * 2;

    cast4_kernel<<<4096, 256, 0, stream>>>(x, xb, 4096 * 1024 / 4);
    transpose_cast_kernel<<<dim3(96, 32), dim3(32, 8), 0, stream>>>(w_qkv, wqkvT, 1024, 3072);
    transpose_cast_kernel<<<dim3(32, 32), dim3(32, 8), 0, stream>>>(w_out, woutT, 1024, 1024);
    gemm_qkv_kernel<<<dim3(32, 24), 256, 0, stream>>>(xb, wqkvT, b_qkv, Qa, Ka, VTa);
    attn_kernel<<<1024, 256, 0, stream>>>(Qa, Ka, VTa, mask, vals);
    gemm_out_kernel<<<dim3(32, 8), 256, 0, stream>>>(vals, woutT, b_out, out);
}

// Round 7
// 240.894 us; speedup vs baseline: 1.8806x; 1.0325x over previous
//
#include <hip/hip_runtime.h>

// MHA: B=2, S=2048, D=1024, H=16, hd=64. fp32 in/out, bf16 MFMA internally.
// R6: (a) GEMMs rebuilt on the attn-proven 4-buffer distance-2 vmcnt pipeline
// (no full-drain barriers in K-loop); (b) gemm_out 128x64 tiles (512 blocks);
// (c) attn: unroll-4 (static LDS offsets), wave-uniform alpha-skip, final
// vmcnt(0) drains before epilogues (LDS-DMA must not outlive the block).

typedef __bf16 bf16;
typedef __bf16 bf16x2 __attribute__((ext_vector_type(2)));
typedef __bf16 bf16x4 __attribute__((ext_vector_type(4)));
typedef __bf16 bf16x8 __attribute__((ext_vector_type(8)));
typedef float f32x4 __attribute__((ext_vector_type(4)));

#define MFMA(a, b, c) __builtin_amdgcn_mfma_f32_16x16x32_bf16((a), (b), (c), 0, 0, 0)

#if __has_builtin(__builtin_amdgcn_exp2f)
#define EXP2(x) __builtin_amdgcn_exp2f(x)
#else
#define EXP2(x) exp2f(x)
#endif

__device__ __forceinline__ void load_lds16(const bf16* g, void* l) {
    __builtin_amdgcn_global_load_lds(
        (const __attribute__((address_space(1))) unsigned int*)g,
        (__attribute__((address_space(3))) unsigned int*)l, 16, 0, 0);
}

// ---------------- cast fp32 -> bf16, 4 elems/thread ----------------
__global__ void cast4_kernel(const float* __restrict__ in, bf16* __restrict__ out, int n4) {
    int i = blockIdx.x * blockDim.x + threadIdx.x;
    if (i < n4) {
        float4 v = ((const float4*)in)[i];
        bf16x4 o = {(bf16)v.x, (bf16)v.y, (bf16)v.z, (bf16)v.w};
        ((bf16x4*)out)[i] = o;
    }
}

// ---------------- transpose + cast: in [R,C] fp32 -> out [C,R] bf16 ----------------
__global__ void transpose_cast_kernel(const float* __restrict__ in, bf16* __restrict__ out,
                                      int R, int C) {
    __shared__ float tile[32][33];
    int bx = blockIdx.x * 32;
    int by = blockIdx.y * 32;
    int tx = threadIdx.x, ty = threadIdx.y;  // (32,8)
    for (int i = 0; i < 32; i += 8)
        tile[ty + i][tx] = in[(size_t)(by + ty + i) * C + bx + tx];
    __syncthreads();
    for (int i = 0; i < 32; i += 8)
        out[(size_t)(bx + ty + i) * R + by + tx] = (bf16)tile[tx][ty + i];
}

// ---------------- GEMM1: X[4096,1024] @ Wqkv -> scatter Q,K,VT (bf16) ----------------
// 128x128 tile, BK=32, K=1024 (32 iters). 4 LDS buffers (A 8K + B 8K each),
// distance-2 global_load_lds prefetch, per-iter: issue 4 -> vmcnt(8) -> barrier.
// Source-side XOR swizzle: slot cc of row holds global chunk cc^(row&3).
__global__ __launch_bounds__(256) void gemm_qkv_kernel(
    const bf16* __restrict__ A, const bf16* __restrict__ BT,
    const float* __restrict__ bias,
    bf16* __restrict__ Q, bf16* __restrict__ K, bf16* __restrict__ VT) {
    __shared__ __attribute__((aligned(16))) char lds[4][16384];  // A[0,8K) B[8K,16K)
    int bm = blockIdx.x, bn = blockIdx.y;
    int t = threadIdx.x;
    int w = t >> 6, lane = t & 63, g = lane >> 4, l16 = lane & 15;
    int wm = (w >> 1) * 64, wn = (w & 1) * 64;
    f32x4 acc[4][4] = {};
    const bf16* Ablk = A + (size_t)(bm * 128) * 1024;
    const bf16* Bblk = BT + (size_t)(bn * 128) * 1024;
    int srow = t >> 2;
    int scg = (t & 3) ^ (srow & 3);
    const bf16* ag0 = Ablk + (size_t)srow * 1024 + scg * 8;
    const bf16* ag1 = ag0 + 64 * 1024;
    const bf16* bg0 = Bblk + (size_t)srow * 1024 + scg * 8;
    const bf16* bg1 = bg0 + 64 * 1024;

    // prologue: stage tiles 0 and 1, full drain
    load_lds16(ag0, lds[0] + t * 16);
    load_lds16(ag1, lds[0] + 4096 + t * 16);
    load_lds16(bg0, lds[0] + 8192 + t * 16);
    load_lds16(bg1, lds[0] + 12288 + t * 16);
    load_lds16(ag0 + 32, lds[1] + t * 16);
    load_lds16(ag1 + 32, lds[1] + 4096 + t * 16);
    load_lds16(bg0 + 32, lds[1] + 8192 + t * 16);
    load_lds16(bg1 + 32, lds[1] + 12288 + t * 16);
    asm volatile("s_waitcnt vmcnt(0)" ::: "memory");
    asm volatile("s_barrier" ::: "memory");

    int sw = l16 & 3;
#pragma unroll 4
    for (int j = 0; j < 32; j++) {
        int buf = j & 3;
        int jp = j + 2 < 32 ? j + 2 : 31;
        char* dst = lds[(j + 2) & 3];
        load_lds16(ag0 + jp * 32, dst + t * 16);
        load_lds16(ag1 + jp * 32, dst + 4096 + t * 16);
        load_lds16(bg0 + jp * 32, dst + 8192 + t * 16);
        load_lds16(bg1 + jp * 32, dst + 12288 + t * 16);
        asm volatile("s_waitcnt vmcnt(8)" ::: "memory");
        asm volatile("s_barrier" ::: "memory");

        const bf16* As = (const bf16*)lds[buf];
        const bf16* Bs = (const bf16*)(lds[buf] + 8192);
        bf16x8 af[4], bfr[4];
#pragma unroll
        for (int mi = 0; mi < 4; mi++) {
            int row = wm + mi * 16 + l16;
            af[mi] = *(const bf16x8*)(&As[row * 32 + (g ^ sw) * 8]);
        }
#pragma unroll
        for (int ni = 0; ni < 4; ni++) {
            int row = wn + ni * 16 + l16;
            bfr[ni] = *(const bf16x8*)(&Bs[row * 32 + (g ^ sw) * 8]);
        }
#pragma unroll
        for (int mi = 0; mi < 4; mi++)
#pragma unroll
            for (int ni = 0; ni < 4; ni++)
                acc[mi][ni] = MFMA(af[mi], bfr[ni], acc[mi][ni]);
    }
    asm volatile("s_waitcnt vmcnt(0)" ::: "memory");

    // epilogue: scatter to Q [bh,s,d], K [bh,s,d], VT [bh,d,s]
    for (int mi = 0; mi < 4; mi++) {
        int row0 = bm * 128 + wm + mi * 16 + g * 4;
        int b = row0 >> 11, s0 = row0 & 2047;
        for (int ni = 0; ni < 4; ni++) {
            int col = bn * 128 + wn + ni * 16 + l16;
            float bv = bias[col];
            int h = col / 192, tt = col % 192;
            size_t bh = (size_t)(b * 16 + h);
            if (tt < 128) {
                bf16* dst = (tt < 64) ? &Q[(bh * 2048 + s0) * 64 + tt]
                                      : &K[(bh * 2048 + s0) * 64 + (tt - 64)];
                for (int r = 0; r < 4; r++)
                    dst[(size_t)r * 64] = (bf16)(acc[mi][ni][r] + bv);
            } else {
                bf16x4 pk = {(bf16)(acc[mi][ni][0] + bv), (bf16)(acc[mi][ni][1] + bv),
                             (bf16)(acc[mi][ni][2] + bv), (bf16)(acc[mi][ni][3] + bv)};
                *(bf16x4*)(&VT[(bh * 64 + (tt - 128)) * 2048 + s0]) = pk;
            }
        }
    }
}

// ---------------- GEMM3: vals[4096,1024] @ Wout -> out fp32 ----------------
// 128x64 tile (grid 32x16 = 512 blocks, 2/CU), BK=32. Same 4-buffer pipeline,
// 3 staging loads per thread per iter (A 2 + B 1) -> vmcnt(6).
__global__ __launch_bounds__(256) void gemm_out_kernel(
    const bf16* __restrict__ A, const bf16* __restrict__ BT,
    const float* __restrict__ bias, float* __restrict__ out) {
    __shared__ __attribute__((aligned(16))) char lds[4][12288];  // A[0,8K) B[8K,12K)
    int bm = blockIdx.x, bn = blockIdx.y;
    int t = threadIdx.x;
    int w = t >> 6, lane = t & 63, g = lane >> 4, l16 = lane & 15;
    int wm = (w >> 1) * 64, wn = (w & 1) * 32;  // wave tile 64x32
    f32x4 acc[4][2] = {};
    const bf16* Ablk = A + (size_t)(bm * 128) * 1024;
    const bf16* Bblk = BT + (size_t)(bn * 64) * 1024;
    int srow = t >> 2;
    int scg = (t & 3) ^ (srow & 3);
    const bf16* ag0 = Ablk + (size_t)srow * 1024 + scg * 8;
    const bf16* ag1 = ag0 + 64 * 1024;
    const bf16* bg0 = Bblk + (size_t)srow * 1024 + scg * 8;  // rows 0..63 only

    load_lds16(ag0, lds[0] + t * 16);
    load_lds16(ag1, lds[0] + 4096 + t * 16);
    load_lds16(bg0, lds[0] + 8192 + t * 16);
    load_lds16(ag0 + 32, lds[1] + t * 16);
    load_lds16(ag1 + 32, lds[1] + 4096 + t * 16);
    load_lds16(bg0 + 32, lds[1] + 8192 + t * 16);
    asm volatile("s_waitcnt vmcnt(0)" ::: "memory");
    asm volatile("s_barrier" ::: "memory");

    int sw = l16 & 3;
#pragma unroll 4
    for (int j = 0; j < 32; j++) {
        int buf = j & 3;
        int jp = j + 2 < 32 ? j + 2 : 31;
        char* dst = lds[(j + 2) & 3];
        load_lds16(ag0 + jp * 32, dst + t * 16);
        load_lds16(ag1 + jp * 32, dst + 4096 + t * 16);
        load_lds16(bg0 + jp * 32, dst + 8192 + t * 16);
        asm volatile("s_waitcnt vmcnt(6)" ::: "memory");
        asm volatile("s_barrier" ::: "memory");

        const bf16* As = (const bf16*)lds[buf];
        const bf16* Bs = (const bf16*)(lds[buf] + 8192);
        bf16x8 af[4], bfr[2];
#pragma unroll
        for (int mi = 0; mi < 4; mi++) {
            int row = wm + mi * 16 + l16;
            af[mi] = *(const bf16x8*)(&As[row * 32 + (g ^ sw) * 8]);
        }
#pragma unroll
        for (int ni = 0; ni < 2; ni++) {
            int row = wn + ni * 16 + l16;
            bfr[ni] = *(const bf16x8*)(&Bs[row * 32 + (g ^ sw) * 8]);
        }
#pragma unroll
        for (int mi = 0; mi < 4; mi++)
#pragma unroll
            for (int ni = 0; ni < 2; ni++)
                acc[mi][ni] = MFMA(af[mi], bfr[ni], acc[mi][ni]);
    }
    asm volatile("s_waitcnt vmcnt(0)" ::: "memory");

    for (int mi = 0; mi < 4; mi++) {
        for (int ni = 0; ni < 2; ni++) {
            int col = bn * 64 + wn + ni * 16 + l16;
            float bv = bias[col];
            for (int r = 0; r < 4; r++) {
                int row = bm * 128 + wm + mi * 16 + g * 4 + r;
                out[(size_t)row * 1024 + col] = acc[mi][ni][r] + bv;
            }
        }
    }
}

// ---------------- flash attention (R6) ----------------
// grid = 1024, block = 256 (4 waves x 16 q-rows). BK=32, 64 iters, unroll 4.
// 4 LDS buffers, distance-2 prefetch, vmcnt(8)+s_barrier per iter.
// Alpha-skip: wave-uniform branch over running-max updates.
__global__ __launch_bounds__(256, 4) void attn_kernel(
    const bf16* __restrict__ Q, const bf16* __restrict__ K,
    const bf16* __restrict__ VT, const float* __restrict__ mask,
    bf16* __restrict__ vals) {
    __shared__ __attribute__((aligned(16))) char lds[4][8192];  // [buf]: K[0,4K) V[4K,8K)

    int blk = blockIdx.x;
    int bh = ((blk & 7) << 2) | ((blk >> 3) & 3);
    int qt = blk >> 5;
    int t = threadIdx.x;
    int w = t >> 6, lane = t & 63, g = lane >> 4, l16 = lane & 15;
    int qw = qt * 64 + w * 16;

    const bf16* Qp = Q + (size_t)bh * 2048 * 64;
    const bf16* Kp = K + (size_t)bh * 2048 * 64;
    const bf16* Vp = VT + (size_t)bh * 64 * 2048;
    const float* mrow = mask + (size_t)(qw + l16) * 2048;

    int ks_row = t >> 3;
    int ks_cblk = (t & 7) ^ (ks_row & 7);
    const bf16* kg = Kp + ks_row * 64 + ks_cblk * 8;
    int vs_d = t >> 2;
    int vs_sblk = (t & 3) ^ ((t >> 3) & 3);
    const bf16* vg = Vp + (size_t)vs_d * 2048 + vs_sblk * 8;

    const float SCL = 0.125f * 1.44269504089f;
    const float L2E = 1.44269504089f;

    bf16x8 q0 = *(const bf16x8*)(&Qp[(size_t)(qw + l16) * 64 + g * 8]);
    bf16x8 q1 = *(const bf16x8*)(&Qp[(size_t)(qw + l16) * 64 + 32 + g * 8]);
    load_lds16(kg + 0, &lds[0][t * 16]);
    load_lds16(vg + 0, &lds[0][4096 + t * 16]);
    float4 mv0 = *(const float4*)(&mrow[0 + g * 4]);
    float4 mv1 = *(const float4*)(&mrow[16 + g * 4]);
    load_lds16(kg + 1 * 32 * 64, &lds[1][t * 16]);
    load_lds16(vg + 1 * 32, &lds[1][4096 + t * 16]);
    asm volatile("s_waitcnt vmcnt(0)" ::: "memory");
    asm volatile("s_barrier" ::: "memory");

    f32x4 o[4] = {};
    float m = -1e30f, l = 0.f;

#pragma unroll 4
    for (int j = 0; j < 64; j++) {
        int buf = j & 3;
        int jm = j + 1 < 64 ? j + 1 : 63;
        float4 nmv0 = *(const float4*)(&mrow[jm * 32 + g * 4]);
        float4 nmv1 = *(const float4*)(&mrow[jm * 32 + 16 + g * 4]);
        int jp = j + 2 < 64 ? j + 2 : 63;
        load_lds16(kg + (size_t)jp * 32 * 64, &lds[(j + 2) & 3][t * 16]);
        load_lds16(vg + jp * 32, &lds[(j + 2) & 3][4096 + t * 16]);
        asm volatile("s_waitcnt vmcnt(8)" ::: "memory");
        asm volatile("s_barrier" ::: "memory");

        float sc[8];
#pragma unroll
        for (int ts = 0; ts < 2; ts++) {
            int s0 = ts * 16 + l16;
            int sw = s0 & 7;
            bf16x8 k0 = *(const bf16x8*)(&lds[buf][(s0 * 8 + (g ^ sw)) * 16]);
            bf16x8 k1 = *(const bf16x8*)(&lds[buf][(s0 * 8 + ((4 + g) ^ sw)) * 16]);
            f32x4 st = {};
            st = MFMA(k0, q0, st);
            st = MFMA(k1, q1, st);
            float4 mv = ts ? *(float4*)&mv1 : *(float4*)&mv0;
            sc[ts * 4 + 0] = st[0] * SCL + mv.x * L2E;
            sc[ts * 4 + 1] = st[1] * SCL + mv.y * L2E;
            sc[ts * 4 + 2] = st[2] * SCL + mv.z * L2E;
            sc[ts * 4 + 3] = st[3] * SCL + mv.w * L2E;
        }

        float vmax = sc[0];
#pragma unroll
        for (int i = 1; i < 8; i++) vmax = fmaxf(vmax, sc[i]);
        vmax = fmaxf(vmax, __shfl_xor(vmax, 16, 64));
        vmax = fmaxf(vmax, __shfl_xor(vmax, 32, 64));
        float mold = m;
        float mn = fmaxf(mold, vmax);
        m = mn;
        float p[8], rs = 0.f;
#pragma unroll
        for (int i = 0; i < 8; i++) { p[i] = EXP2(sc[i] - mn); rs += p[i]; }
        rs += __shfl_xor(rs, 16, 64);
        rs += __shfl_xor(rs, 32, 64);
        if (__any(vmax > mold)) {   // wave-uniform: rescale only when max moved
            float alpha = EXP2(mold - mn);
            l = l * alpha + rs;
#pragma unroll
            for (int nc = 0; nc < 4; nc++) {
                o[nc][0] *= alpha; o[nc][1] *= alpha;
                o[nc][2] *= alpha; o[nc][3] *= alpha;
            }
        } else {
            l += rs;
        }

        int dw0, dw1, dw2, dw3;
        { union { bf16x2 h; int i; } u;
          u.h = bf16x2{(bf16)p[0], (bf16)p[1]}; dw0 = u.i;
          u.h = bf16x2{(bf16)p[2], (bf16)p[3]}; dw1 = u.i;
          u.h = bf16x2{(bf16)p[4], (bf16)p[5]}; dw2 = u.i;
          u.h = bf16x2{(bf16)p[6], (bf16)p[7]}; dw3 = u.i; }
        int selA = (((2 * g) & 3) << 4) | l16;
        int selB = (((2 * g + 1) & 3) << 4) | l16;
        int t0a = __shfl(dw0, selA, 64), t2a = __shfl(dw2, selA, 64);
        int t1a = __shfl(dw1, selA, 64), t3a = __shfl(dw3, selA, 64);
        int t0b = __shfl(dw0, selB, 64), t2b = __shfl(dw2, selB, 64);
        int t1b = __shfl(dw1, selB, 64), t3b = __shfl(dw3, selB, 64);
        bool hi = (g & 2) != 0;
        union { int i[4]; bf16x8 v; } pu;
        pu.i[0] = hi ? t2a : t0a;
        pu.i[1] = hi ? t3a : t1a;
        pu.i[2] = hi ? t2b : t0b;
        pu.i[3] = hi ? t3b : t1b;

#pragma unroll
        for (int nc = 0; nc < 4; nc++) {
            int d = nc * 16 + l16;
            int slot = d * 4 + (g ^ ((d >> 1) & 3));
            bf16x8 vf = *(const bf16x8*)(&lds[buf][4096 + slot * 16]);
            o[nc] = MFMA(vf, pu.v, o[nc]);
        }

        mv0 = nmv0;
        mv1 = nmv1;
    }
    asm volatile("s_waitcnt vmcnt(0)" ::: "memory");

    int b = bh >> 4, h = bh & 15;
    float linv = 1.f / l;
    size_t row = (size_t)(b * 2048 + qw + l16);
#pragma unroll
    for (int nc = 0; nc < 4; nc++) {
        bf16x4 pk = {(bf16)(o[nc][0] * linv), (bf16)(o[nc][1] * linv),
                     (bf16)(o[nc][2] * linv), (bf16)(o[nc][3] * linv)};
        *(bf16x4*)(&vals[row * 1024 + h * 64 + nc * 16 + g * 4]) = pk;
    }
}

// ---------------- launch ----------------
extern "C" void kernel_launch(void* const* d_in, const int* in_sizes, int n_in,
                              void* d_out, int out_size, void* d_ws, size_t ws_size,
                              hipStream_t stream) {
    const float* x     = (const float*)d_in[0];
    const float* mask  = (const float*)d_in[1];
    const float* w_qkv = (const float*)d_in[2];
    const float* b_qkv = (const float*)d_in[3];
    const float* w_out = (const float*)d_in[4];
    const float* b_out = (const float*)d_in[5];
    float* out = (float*)d_out;

    char* ws = (char*)d_ws;
    size_t off = 0;
    bf16* xb    = (bf16*)(ws + off); off += (size_t)4096 * 1024 * 2;
    bf16* wqkvT = (bf16*)(ws + off); off += (size_t)3072 * 1024 * 2;
    bf16* woutT = (bf16*)(ws + off); off += (size_t)1024 * 1024 * 2;
    bf16* Qa    = (bf16*)(ws + off); off += (size_t)32 * 2048 * 64 * 2;
    bf16* Ka    = (bf16*)(ws + off); off += (size_t)32 * 2048 * 64 * 2;
    bf16* VTa   = (bf16*)(ws + off); off += (size_t)32 * 64 * 2048 * 2;
    bf16* vals  = (bf16*)(ws + off); off += (size_t)4096 * 1024 * 2;

    cast4_kernel<<<4096, 256, 0, stream>>>(x, xb, 4096 * 1024 / 4);
    transpose_cast_kernel<<<dim3(96, 32), dim3(32, 8), 0, stream>>>(w_qkv, wqkvT, 1024, 3072);
    transpose_cast_kernel<<<dim3(32, 32), dim3(32, 8), 0, stream>>>(w_out, woutT, 1024, 1024);
    gemm_qkv_kernel<<<dim3(32, 24), 256, 0, stream>>>(xb, wqkvT, b_qkv, Qa, Ka, VTa);
    attn_kernel<<<1024, 256, 0, stream>>>(Qa, Ka, VTa, mask, vals);
    gemm_out_kernel<<<dim3(32, 16), 256, 0, stream>>>(vals, woutT, b_out, out);
}